// Round 11
// baseline (210.886 us; speedup 1.0000x reference)
//
#include <hip/hip_runtime.h>
#include <math.h>

// MoBA attention, round 20: prologue slimming + wave-causal skip + vcombine.
// vs r19 (verified structure kept throughout):
// - prologue: msk array + its barrier removed; every thread computes its own
//   q-row's top-k argmax directly from dsc (identical fp64 values -> bit-
//   identical masks). dsc padded to stride 9 (r19's [n*64+qi] write pattern
//   was an 8-way bank conflict -> +330K conflict cycles).
// - wave-causal skip: cur-block chunks with kb > qw0+15 are provable no-ops
//   (all scores masked to -inf => p=0, fast path, oacc unchanged) -> skip.
// - attn_combine_k vectorized float4/ushort4, grid 6144 -> 1536.
// preproc/qkv/out/main-loop: r19 verbatim.

#define HID   768
#define NH    12
#define DH    64
#define SEQN  2048
#define BATCH 2
#define NTOK  (BATCH*SEQN)   // 4096
#define NB    8
#define BLKSZ 256
#define NEG_INF (-__builtin_huge_valf())
#define POS_INF (__builtin_huge_valf())
#define LO_SCALE 2048.0f
#define LO_INV   (1.0f/2048.0f)
#define EXP2C    0.18033688f   // 0.125 * log2(e)

// split geometry: per bh, q-rows 1024..2047 are split 2-way
#define SPLIT_ROWS 1024
#define NBH   (BATCH*NH)       // 24

typedef unsigned short u16;
typedef _Float16 v8hf __attribute__((ext_vector_type(8)));
typedef float    v4f  __attribute__((ext_vector_type(4)));

__device__ __forceinline__ u16 f2h(float x) {
    _Float16 h = (_Float16)x;
    return __builtin_bit_cast(u16, h);
}
__device__ __forceinline__ float h2f(u16 u) {
    return (float)__builtin_bit_cast(_Float16, u);
}
__device__ __forceinline__ v8hf ldhf8(const u16* p) {
    return *reinterpret_cast<const v8hf*>(p);
}
__device__ __forceinline__ void g2lds16(const u16* g, u16* l) {
    __builtin_amdgcn_global_load_lds(
        (const __attribute__((address_space(1))) void*)g,
        (__attribute__((address_space(3))) void*)l, 16, 0, 0);
}
#define MFMA16(a, b, c) __builtin_amdgcn_mfma_f32_16x16x32_f16(a, b, c, 0, 0, 0)

// heavy-first permutation: slot -> round-10 unit id (u<16: unsplit qb=u;
// u>=16: qb=16+((u-16)>>1), split=(u-16)&1). Ordered by descending static
// tile upper-bound: ub_unsplit(qb)=qb+1, ub_split(qb)=(qb+2)>>1.
__device__ const int g_uord[48] = {
    46,47,44,45,15,  // ub 16: qb31 s0/s1, qb30 s0/s1, qb15
    42,43,40,41,14,  // ub 15
    38,39,36,37,13,  // ub 14
    34,35,32,33,12,  // ub 13
    30,31,28,29,11,  // ub 12
    26,27,24,25,10,  // ub 11
    22,23,20,21, 9,  // ub 10
    18,19,16,17, 8,  // ub  9
     7, 6, 5, 4, 3, 2, 1, 0
};

// ---------------------------------------------------------------------------
// Fused preprocessing, x4-vectorized: X split (blocks 0-3071), W splits
// (3072-5375), RoPE table (5376-5631).
__global__ __launch_bounds__(256)
void preproc_k(const float* __restrict__ X,  const float* __restrict__ Wq,
               const float* __restrict__ Wk, const float* __restrict__ Wv,
               const float* __restrict__ Wo, float2* __restrict__ tab,
               u16* __restrict__ Xh, u16* __restrict__ Xl,
               u16* __restrict__ Wq2, u16* __restrict__ Wk2,
               u16* __restrict__ Wv2, u16* __restrict__ Wo2)
{
    const int NW = HID * HID;
    const int id = blockIdx.x;
    const int tid = threadIdx.x;
    if (id < 3072) {                        // X -> f16 hi/lo(x2048), 4 elems
        const int i = (id * 256 + tid) * 4;
        const float4 x4 = *(const float4*)&X[i];
        const float xf[4] = {x4.x, x4.y, x4.z, x4.w};
        ushort4 h4, l4;
        u16* hp = (u16*)&h4; u16* lp = (u16*)&l4;
        #pragma unroll
        for (int j = 0; j < 4; j++) {
            const u16 h = f2h(xf[j]);
            hp[j] = h;
            lp[j] = f2h((xf[j] - h2f(h)) * LO_SCALE);
        }
        *(ushort4*)&Xh[i] = h4;
        *(ushort4*)&Xl[i] = l4;
    } else if (id < 5376) {                 // 4 weight splits, 4 elems
        const int j4 = ((id - 3072) * 256 + tid) * 4;
        const int z = j4 / NW, i = j4 - z * NW;
        const float* src = (z == 0) ? Wq : (z == 1) ? Wk : (z == 2) ? Wv : Wo;
        u16* dst = (z == 0) ? Wq2 : (z == 1) ? Wk2 : (z == 2) ? Wv2 : Wo2;
        const float4 x4 = *(const float4*)&src[i];
        const float xf[4] = {x4.x, x4.y, x4.z, x4.w};
        ushort4 h4, l4;
        u16* hp = (u16*)&h4; u16* lp = (u16*)&l4;
        #pragma unroll
        for (int j = 0; j < 4; j++) {
            const u16 h = f2h(xf[j]);
            hp[j] = h;
            lp[j] = f2h((xf[j] - h2f(h)) * LO_SCALE);
        }
        *(ushort4*)&dst[i] = h4;
        *(ushort4*)&dst[i + NW] = l4;
    } else {                                // RoPE table (numpy fp32 op order)
        const int i = (id - 5376) * 256 + tid;
        const int s = i >> 5, f = i & 31;
        const double y  = exp((double)f * (log(10000.0) / 32.0));
        const float yf = (float)y;
        const float invf = 1.0f / yf;
        const float ang  = (float)s * invf;
        tab[i] = make_float2((float)sin((double)ang), (float)cos((double)ang));
    }
}

// ---------------------------------------------------------------------------
// Single-pass 128x64 dual-split mainloop. Per K-chunk both A splits (hi,lo)
// and both B splits are staged; products accumulate into acc01 (lo-pair) and
// acc2 (hi*hi). hasC0=false (V) skips the Al*Bh product and Al staging.
__device__ __forceinline__
void qkv_mainloop(const u16* __restrict__ Ah, const u16* __restrict__ Al,
                  const u16* __restrict__ Bh, const u16* __restrict__ Bl,
                  int m0, int nb0, bool hasC0,
                  u16* As, u16* Bs, v4f acc01[2][4], v4f acc2[2][4])
{
    const int tid = threadIdx.x;
    const int w = tid >> 6, lane = tid & 63;
    const int col = lane & 15, quad = lane >> 4;
    const int AOFF = 128 * 64, BOFF = 64 * 64;

    int a_row[4], a_gl[4];
    #pragma unroll
    for (int r = 0; r < 4; r++) {
        const int g = r * 256 + tid;
        a_row[r] = g >> 3;
        a_gl[r]  = (g & 7) ^ (a_row[r] & 7);
    }
    int b_row[2], b_gl[2];
    #pragma unroll
    for (int r = 0; r < 2; r++) {
        const int g = r * 256 + tid;
        b_row[r] = g >> 3;
        b_gl[r]  = (g & 7) ^ (b_row[r] & 7);
    }

    for (int itc = 0; itc < HID / 64; itc++) {
        const int k0 = itc * 64;
        __syncthreads();
        #pragma unroll
        for (int r = 0; r < 4; r++)
            g2lds16(Ah + (size_t)(m0 + a_row[r]) * HID + k0 + a_gl[r] * 8,
                    &As[(r * 256 + w * 64) * 8]);
        if (hasC0) {
            #pragma unroll
            for (int r = 0; r < 4; r++)
                g2lds16(Al + (size_t)(m0 + a_row[r]) * HID + k0 + a_gl[r] * 8,
                        &As[AOFF + (r * 256 + w * 64) * 8]);
        }
        #pragma unroll
        for (int r = 0; r < 2; r++) {
            g2lds16(Bh + (size_t)(nb0 + b_row[r]) * HID + k0 + b_gl[r] * 8,
                    &Bs[(r * 256 + w * 64) * 8]);
            g2lds16(Bl + (size_t)(nb0 + b_row[r]) * HID + k0 + b_gl[r] * 8,
                    &Bs[BOFF + (r * 256 + w * 64) * 8]);
        }
        __syncthreads();
        #pragma unroll
        for (int ks = 0; ks < 2; ks++) {
            v8hf afh[2], afl[2], bfh[4], bfl[4];
            #pragma unroll
            for (int mt = 0; mt < 2; mt++) {
                const int row = w * 32 + mt * 16 + col;
                const int gph = (ks * 4 + quad) ^ (row & 7);
                afh[mt] = ldhf8(&As[row * 64 + gph * 8]);
                if (hasC0) afl[mt] = ldhf8(&As[AOFF + row * 64 + gph * 8]);
            }
            #pragma unroll
            for (int nt = 0; nt < 4; nt++) {
                const int row = nt * 16 + col;
                const int gph = (ks * 4 + quad) ^ (row & 7);
                bfh[nt] = ldhf8(&Bs[row * 64 + gph * 8]);
                bfl[nt] = ldhf8(&Bs[BOFF + row * 64 + gph * 8]);
            }
            #pragma unroll
            for (int mt = 0; mt < 2; mt++)
                #pragma unroll
                for (int nt = 0; nt < 4; nt++) {
                    if (hasC0)
                        acc01[mt][nt] = MFMA16(afl[mt], bfh[nt], acc01[mt][nt]);
                    acc01[mt][nt] = MFMA16(afh[mt], bfl[nt], acc01[mt][nt]);
                    acc2[mt][nt]  = MFMA16(afh[mt], bfh[nt], acc2[mt][nt]);
                }
        }
    }
    __syncthreads();
}

// ---------------------------------------------------------------------------
// Fused QKV. grid = 1152: 36 n-tiles (Q 0-11, K 12-23, V 24-35) x 32 m-tiles,
// XCD-partitioned by m. Single-pass dual-split staging (48 KB LDS).
__global__ __launch_bounds__(256, 3)
void qkv_fused_gemm_k(const u16* __restrict__ Xh, const u16* __restrict__ Xl,
                      const u16* __restrict__ Wq2, const u16* __restrict__ Wk2,
                      const u16* __restrict__ Wv2, const float2* __restrict__ tab,
                      float* __restrict__ q32, u16* __restrict__ kh16,
                      u16* __restrict__ vth, float* __restrict__ partial)
{
    __shared__ u16 As[2 * 128 * 64];   // 32 KB (hi | lo)
    __shared__ u16 Bs[2 * 64 * 64];    // 16 KB (hi | lo)
    float (*psum)[64] = (float(*)[64])As;   // overlay: post-loop use only

    const int NW = HID * HID;
    const int id    = blockIdx.x;
    const int xcd   = id & 7, loc = id >> 3;      // 144 per XCD
    const int mtile = xcd * 4 + (loc & 3);
    const int ntile = loc >> 2;                   // 0..35
    const int m0  = mtile * 128;
    const int mat = ntile / 12;
    const int nb0 = (ntile - mat * 12) * 64;
    const u16* Bh = (mat == 0) ? Wq2 : (mat == 1) ? Wk2 : Wv2;

    v4f acc01[2][4] = {}, acc2[2][4] = {};
    qkv_mainloop(Xh, Xl, Bh, Bh + NW, m0, nb0, mat != 2, As, Bs, acc01, acc2);

    v4f acc[2][4];
    #pragma unroll
    for (int mt = 0; mt < 2; mt++)
        #pragma unroll
        for (int nt = 0; nt < 4; nt++)
            #pragma unroll
            for (int r = 0; r < 4; r++)
                acc[mt][nt][r] = acc01[mt][nt][r] * LO_INV + acc2[mt][nt][r];

    const int tid = threadIdx.x;
    const int w = tid >> 6, lane = tid & 63;
    const int col = lane & 15, quad = lane >> 4;
    const int b = m0 >> 11;
    const int h = nb0 >> 6;
    const size_t bh = (size_t)b * NH + h;

    if (mat == 2) {                // V: transposed f16 store
        #pragma unroll
        for (int nt = 0; nt < 4; nt++) {
            const int d = nt * 16 + col;
            #pragma unroll
            for (int mt = 0; mt < 2; mt++) {
                const int m = m0 + w * 32 + mt * 16 + quad * 4;
                const int s = m & (SEQN - 1);
                ushort4 pk = make_ushort4(f2h(acc[mt][nt][0]), f2h(acc[mt][nt][1]),
                                          f2h(acc[mt][nt][2]), f2h(acc[mt][nt][3]));
                *(ushort4*)&vth[(bh * DH + d) * SEQN + s] = pk;
            }
        }
        return;
    }

    // Q/K: RoPE (partner dim d^32 = acc[mt][nt^2], same lane)
    float vsum[4] = {0.f, 0.f, 0.f, 0.f};
    #pragma unroll
    for (int mt = 0; mt < 2; mt++) {
        #pragma unroll
        for (int nt = 0; nt < 4; nt++) {
            const int d = nt * 16 + col;
            #pragma unroll
            for (int r = 0; r < 4; r++) {
                const int m = m0 + w * 32 + mt * 16 + quad * 4 + r;
                const int s = m & (SEQN - 1);
                const float part = acc[mt][nt ^ 2][r];
                const float2 sc = tab[(s << 5) + (d & 31)];
                const float val = (d < 32) ? acc[mt][nt][r] * sc.y - part * sc.x
                                           : acc[mt][nt][r] * sc.y + part * sc.x;
                const size_t idx = (bh * SEQN + s) * DH + d;
                if (mat == 0) {
                    q32[idx] = val;
                } else {
                    kh16[idx] = f2h(val);
                    vsum[nt] += val;
                }
            }
        }
    }
    if (mat == 1) {                // deterministic 128-token block partials
        #pragma unroll
        for (int nt = 0; nt < 4; nt++) {
            float v = vsum[nt];
            v += __shfl_xor(v, 16);
            v += __shfl_xor(v, 32);
            if (quad == 0) psum[w][nt * 16 + col] = v;
        }
        __syncthreads();
        if (tid < 64) {
            const float s4 = (psum[0][tid] + psum[1][tid])
                           + (psum[2][tid] + psum[3][tid]);
            const int nblk = (m0 & (SEQN - 1)) >> 8;
            const int half = (m0 >> 7) & 1;
            partial[((bh * NB + nblk) * 2 + half) * 64 + tid] = s4;
        }
    }
}

// ---------------------------------------------------------------------------
// Output projection: 64x64 tiles, 768 wgs (3/CU), single-pass dual-split.
__global__ __launch_bounds__(256, 3)
void out_gemm_mfma_k(const u16* __restrict__ Ah, const u16* __restrict__ Wo2,
                     float* __restrict__ C)
{
    __shared__ u16 As[64 * 64];        // 8 KB
    __shared__ u16 Bs[2 * 64 * 64];    // 16 KB (hi | lo)
    const int BOFF = 64 * 64;

    const int NW = HID * HID;
    const int id    = blockIdx.x;                 // 768
    const int xcd   = id & 7, loc = id >> 3;      // 96 per XCD
    const int mtile = xcd * 8 + (loc & 7);        // 64 m-tiles
    const int ntile = loc >> 3;                   // 0..11
    const int m0 = mtile * 64, n0 = ntile * 64;
    const int tid = threadIdx.x;
    const int w = tid >> 6, lane = tid & 63;
    const int col = lane & 15, quad = lane >> 4;

    const int r0 = tid >> 3,         gl0 = (tid & 7) ^ (r0 & 7);
    const int r1 = (256 + tid) >> 3, gl1 = ((256 + tid) & 7) ^ (r1 & 7);

    const u16* Bhp = Wo2;            // hi
    const u16* Blp = Wo2 + NW;       // lo

    v4f accL[4] = {}, accH[4] = {};
    for (int itc = 0; itc < HID / 64; itc++) {
        const int k0 = itc * 64;
        __syncthreads();
        g2lds16(Ah  + (size_t)(m0 + r0) * HID + k0 + gl0 * 8, &As[(w * 64) * 8]);
        g2lds16(Ah  + (size_t)(m0 + r1) * HID + k0 + gl1 * 8, &As[(256 + w * 64) * 8]);
        g2lds16(Bhp + (size_t)(n0 + r0) * HID + k0 + gl0 * 8, &Bs[(w * 64) * 8]);
        g2lds16(Bhp + (size_t)(n0 + r1) * HID + k0 + gl1 * 8, &Bs[(256 + w * 64) * 8]);
        g2lds16(Blp + (size_t)(n0 + r0) * HID + k0 + gl0 * 8, &Bs[BOFF + (w * 64) * 8]);
        g2lds16(Blp + (size_t)(n0 + r1) * HID + k0 + gl1 * 8, &Bs[BOFF + (256 + w * 64) * 8]);
        __syncthreads();
        #pragma unroll
        for (int ks = 0; ks < 2; ks++) {
            const int arow = w * 16 + col;
            v8hf a = ldhf8(&As[arow * 64 + (((ks * 4 + quad) ^ (arow & 7))) * 8]);
            #pragma unroll
            for (int nt = 0; nt < 4; nt++) {
                const int row = nt * 16 + col;
                const int g = (ks * 4 + quad) ^ (row & 7);
                accH[nt] = MFMA16(a, ldhf8(&Bs[row * 64 + g * 8]), accH[nt]);
                accL[nt] = MFMA16(a, ldhf8(&Bs[BOFF + row * 64 + g * 8]), accL[nt]);
            }
        }
    }

    #pragma unroll
    for (int nt = 0; nt < 4; nt++)
        #pragma unroll
        for (int r = 0; r < 4; r++) {
            const int m = m0 + w * 16 + quad * 4 + r;
            C[(size_t)m * HID + n0 + nt * 16 + col] =
                accL[nt][r] * LO_INV + accH[nt][r];
        }
}

// ---------------------------------------------------------------------------
// f16 MFMA flash attention (r16 mainloop: double-buffered K+V, one
// __syncthreads per tile, heavy-first order, 40 KB LDS, 4 blocks/CU) with
// parallel inline reps+top-k prologue (per-thread argmax, 3 barriers),
// defer-max softmax, and wave-causal tile skip. grid = 1152.
__global__ __launch_bounds__(256, 4)
void moba_attn_k(const float* __restrict__ q32, const u16* __restrict__ kh16,
                 const u16* __restrict__ vth, const float* __restrict__ partial,
                 u16* __restrict__ aoh, float* __restrict__ po,
                 float* __restrict__ ml)
{
    __shared__ u16 kbuf[2][64 * 64];
    __shared__ u16 vbuf[2][64 * 64];
    __shared__ u16 plds[4][16][64];
    // prologue overlays (all dead before first stage(); fenced by barriers):
    unsigned* s_uni = (unsigned*)&plds[0][0][0];
    float (*rs)[DH + 4] = (float(*)[DH + 4])&kbuf[0][0];  // 8x68 fl = 2176 B
    double* dsc     = (double*)&kbuf[1][0];               // [qi*9+n], 4608 B
    float4* qv4     = (float4*)&vbuf[0][0];               // 64 rows x 16 f4,
                                                          // XOR-swizzled

    const int id  = blockIdx.x;                 // 0..1151
    const int xcd = id & 7, loc = id >> 3;      // 0..143
    const int bh  = xcd * 3 + loc / 48;
    const int u   = g_uord[loc % 48];           // heavy-first permutation
    int qb, split, stride;
    if (u < 16) { qb = u;                 split = 0;          stride = 1; }
    else        { qb = 16 + ((u - 16) >> 1); split = (u - 16) & 1; stride = 2; }
    const int q0  = qb * 64;
    const int cur = q0 >> 8;
    const int tid = threadIdx.x;
    const int wave = tid >> 6, lane = tid & 63;
    const int col = lane & 15, quad = lane >> 4;
    const int qw0 = q0 + wave * 16;
    const int qpos = qw0 + col;
    const size_t bhS = (size_t)bh * SEQN;
    const size_t bhV = (size_t)bh * DH;

    // --- prologue: stage Q (swizzled) + reps (padded rows) ---
    if (tid == 0) *s_uni = 0;
    {
        const float4* src = (const float4*)&q32[(bhS + q0) * DH];
        #pragma unroll
        for (int i = 0; i < 4; i++) {
            const int L = tid + i * 256;            // 0..1023
            const int r = L >> 4, j = L & 15;
            qv4[r * 16 + (j ^ (r & 7))] = src[L];
        }
    }
    for (int idx = tid; idx < NB * DH; idx += 256) {
        const int n = idx >> 6, d = idx & 63;
        const float* pp = &partial[(size_t)((bh * NB + n) * 2) * 64 + d];
        const double s = (double)pp[0] + (double)pp[64];
        rs[n][d] = (float)(s * (1.0 / 256.0));
    }
    __syncthreads();

    // 512 dots (q-row qi, block n), 2/thread; per-dot d-ascending fp64 order
    // identical to the standalone select_topk_k -> bit-identical masks.
    #pragma unroll
    for (int hh = 0; hh < 2; hh++) {
        const int e = tid + hh * 256;               // 0..511
        const int qi = e >> 3, n = e & 7;
        double s = 0.0;
        for (int c = 0; c < 16; c++) {
            const float4 a = qv4[qi * 16 + (c ^ (qi & 7))];
            const float4 b = *(const float4*)&rs[n][c * 4];
            s += (double)a.x * (double)b.x;
            s += (double)a.y * (double)b.y;
            s += (double)a.z * (double)b.z;
            s += (double)a.w * (double)b.w;
        }
        dsc[qi * 9 + n] = s;
    }
    __syncthreads();

    // per-thread argmax for this thread's own q-row (wave*16+col); quads
    // duplicate (LDS broadcast). No msk array / extra barrier needed.
    unsigned mymask;
    {
        const int qrow = wave * 16 + col;
        double sc[NB];
        #pragma unroll
        for (int n = 0; n < NB; n++) sc[n] = dsc[qrow * 9 + n] * 0.125;
        for (int n = cur + 1; n < NB; n++) sc[n] = -1e300;
        sc[cur] = 1e300;
        unsigned m = 0;
        for (int p = 0; p < 3; p++) {
            int bi = -1; double bv = 0.0;
            for (int n = 0; n < NB; n++) {
                if ((m >> n) & 1) continue;
                if (bi < 0 || sc[n] > bv) { bi = n; bv = sc[n]; }
            }
            m |= 1u << bi;
        }
        mymask = m;
    }

    unsigned uw = mymask;
    #pragma unroll
    for (int off = 1; off < 16; off <<= 1) uw |= __shfl_xor(uw, off);
    if (lane == 0) atomicOr(s_uni, uw);
    const unsigned wmask = __builtin_amdgcn_readfirstlane(uw);  // wave's 16-q union

    v8hf qh[2], ql[2];
    {
        const int qrow = wave * 16 + col;
        #pragma unroll
        for (int ks = 0; ks < 2; ks++) {
            const int j0 = ks * 8 + quad * 2;
            const float4 f0 = qv4[qrow * 16 + (j0 ^ (qrow & 7))];
            const float4 f1 = qv4[qrow * 16 + ((j0 + 1) ^ (qrow & 7))];
            float qf[8] = {f0.x, f0.y, f0.z, f0.w, f1.x, f1.y, f1.z, f1.w};
            union { u16 u[8]; v8hf h; } uh, ul;
            #pragma unroll
            for (int j = 0; j < 8; j++) {
                u16 hb = f2h(qf[j]);
                uh.u[j] = hb;
                ul.u[j] = f2h((qf[j] - h2f(hb)) * LO_SCALE);
            }
            qh[ks] = uh.h; ql[ks] = ul.h;
        }
    }
    __syncthreads();   // s_uni final; qv4/dsc reads done (bufs reusable)
    const unsigned uni = __builtin_amdgcn_readfirstlane(*s_uni);

    // tile enumerator: split s starts at tile index s, advances by `stride`
    int n_nxt = __builtin_ctz(uni), c_nxt = 0;
    bool has_nxt = true;
    auto c2max = [&](int n) { return (n == cur) ? ((q0 + 63 - n * BLKSZ) >> 6) : 3; };
    auto advance1 = [&]() {
        if (c_nxt < c2max(n_nxt)) { c_nxt++; return; }
        for (int nn = n_nxt + 1; nn < NB; nn++)
            if ((uni >> nn) & 1) { n_nxt = nn; c_nxt = 0; return; }
        has_nxt = false;
    };
    for (int i = 0; i < split; i++) if (has_nxt) advance1();
    int n_cur = n_nxt, c_cur = c_nxt;
    const bool cur_valid = has_nxt;

    const size_t srow0 = (size_t)bh * SPLIT_ROWS + (q0 - SPLIT_ROWS);  // split rows only

    if (!cur_valid) {   // empty split (defensive; cur block always has >=1 tile)
        if (stride == 2) {
            if (quad == 0) {
                const size_t r = srow0 + wave * 16 + col;
                ml[(r * 2 + split) * 2 + 0] = NEG_INF;
                ml[(r * 2 + split) * 2 + 1] = 0.f;
            }
            #pragma unroll
            for (int nt = 0; nt < 4; nt++)
                #pragma unroll
                for (int r = 0; r < 4; r++) {
                    const size_t rq = srow0 + wave * 16 + quad * 4 + r;
                    po[(rq * 2 + split) * 64 + nt * 16 + col] = 0.f;
                }
        }
        return;
    }
    for (int i = 0; i < stride; i++) if (has_nxt) advance1();

    const int sg_row0 = tid >> 3;
    const int sg_gl0  = (tid & 7) ^ (sg_row0 & 7);
    const int sg_row1 = (256 + tid) >> 3;
    const int sg_gl1  = ((256 + tid) & 7) ^ (sg_row1 & 7);
    auto stage = [&](int n, int c2, int buf) {
        const int kb = n * BLKSZ + c2 * 64;
        u16* kd = (u16*)kbuf[buf];
        u16* vd = (u16*)vbuf[buf];
        const size_t ks0 = (bhS + kb + sg_row0) * DH + sg_gl0 * 8;
        const size_t ks1 = (bhS + kb + sg_row1) * DH + sg_gl1 * 8;
        const size_t vs0 = (bhV + sg_row0) * SEQN + kb + sg_gl0 * 8;
        const size_t vs1 = (bhV + sg_row1) * SEQN + kb + sg_gl1 * 8;
        g2lds16(kh16 + ks0, kd + (wave * 64) * 8);
        g2lds16(kh16 + ks1, kd + (256 + wave * 64) * 8);
        g2lds16(vth + vs0, vd + (wave * 64) * 8);
        g2lds16(vth + vs1, vd + (256 + wave * 64) * 8);
    };

    const v4f zero4 = {0.f, 0.f, 0.f, 0.f};
    v4f oacc[4] = {zero4, zero4, zero4, zero4};
    float m_i = NEG_INF, l_i = 0.f;
    const int psw = (col & 7) << 1;

    stage(n_cur, c_cur, 0);
    int t = 0;
    while (true) {
        __syncthreads();
        if (has_nxt) stage(n_nxt, c_nxt, (t + 1) & 1);

        const int n  = n_cur;
        const int kb = n * BLKSZ + c_cur * 64;
        const bool iscur = (n == cur);
        const float selinf = ((mymask >> n) & 1) ? 0.f : POS_INF;
        const bool need_mask = iscur && (kb + 63 > qw0);
        const u16* kd = (const u16*)kbuf[t & 1];
        const u16* vd = (const u16*)vbuf[t & 1];

        // skip body if none of this wave's 16 queries select block n, or the
        // chunk is entirely beyond this wave's causal range (kb > qw0+15:
        // all scores masked to -inf => p=0, rm=-inf => m,l,oacc unchanged).
        if (((wmask >> n) & 1) && (!iscur || kb <= qw0 + 15)) {
            v4f sf[4];
            __builtin_amdgcn_s_setprio(1);
            #pragma unroll
            for (int mt = 0; mt < 4; mt++) {
                const int row = mt * 16 + col;
                const int r7 = row & 7;
                v8hf kh0 = ldhf8(&kd[(row * 8 + (quad ^ r7)) * 8]);
                v8hf kh1 = ldhf8(&kd[(row * 8 + ((4 + quad) ^ r7)) * 8]);
                v4f c = zero4;
                c = MFMA16(kh0, ql[0], c);
                c = MFMA16(kh1, ql[1], c);
                #pragma unroll
                for (int r = 0; r < 4; r++) c[r] *= LO_INV;
                c = MFMA16(kh0, qh[0], c);
                c = MFMA16(kh1, qh[1], c);
                sf[mt] = c;
            }
            __builtin_amdgcn_s_setprio(0);

            if (need_mask) {
                #pragma unroll
                for (int mt = 0; mt < 4; mt++)
                    #pragma unroll
                    for (int r = 0; r < 4; r++) {
                        const int kidx = kb + mt * 16 + quad * 4 + r;
                        sf[mt][r] = (kidx <= qpos) ? sf[mt][r] : NEG_INF;
                    }
            }

            // tree max (depth 4 instead of 16)
            const float t0 = fmaxf(fmaxf(sf[0][0], sf[0][1]), fmaxf(sf[0][2], sf[0][3]));
            const float t1 = fmaxf(fmaxf(sf[1][0], sf[1][1]), fmaxf(sf[1][2], sf[1][3]));
            const float t2 = fmaxf(fmaxf(sf[2][0], sf[2][1]), fmaxf(sf[2][2], sf[2][3]));
            const float t3 = fmaxf(fmaxf(sf[3][0], sf[3][1]), fmaxf(sf[3][2], sf[3][3]));
            float rm = fmaxf(fmaxf(t0, t1), fmaxf(t2, t3));
            rm = fmaxf(rm, __shfl_xor(rm, 16));
            rm = fmaxf(rm, __shfl_xor(rm, 32));
            rm = rm - selinf;

            // defer-max: skip rescale when no lane's max grew by > 8
            // (p then bounded by e^1; m/l/oacc bias consistency kept)
            const bool fast = __all(rm <= m_i + 8.0f) != 0;
            float mnew = m_i, alpha = 1.f;
            if (!fast) {
                mnew  = fmaxf(m_i, rm);
                alpha = (m_i == NEG_INF) ? 0.f : exp2f((m_i - mnew) * EXP2C);
            }
            const float biasC = ((mnew == NEG_INF) ? 0.f : mnew * EXP2C) + selinf;

            float lmt[4];
            #pragma unroll
            for (int mt = 0; mt < 4; mt++) {
                ushort4 hv;
                float p0 = exp2f(fmaf(sf[mt][0], EXP2C, -biasC));
                float p1 = exp2f(fmaf(sf[mt][1], EXP2C, -biasC));
                float p2 = exp2f(fmaf(sf[mt][2], EXP2C, -biasC));
                float p3 = exp2f(fmaf(sf[mt][3], EXP2C, -biasC));
                hv.x = f2h(p0); hv.y = f2h(p1); hv.z = f2h(p2); hv.w = f2h(p3);
                lmt[mt] = (p0 + p1) + (p2 + p3);
                *(ushort4*)&plds[wave][col][((mt * 4 + quad) ^ psw) * 4] = hv;
            }
            float lsum = (lmt[0] + lmt[1]) + (lmt[2] + lmt[3]);
            lsum += __shfl_xor(lsum, 16);
            lsum += __shfl_xor(lsum, 32);

            if (fast) {
                l_i = l_i + lsum;
            } else {
                l_i = l_i * alpha + lsum;
                m_i = mnew;
                float ar[4];
                #pragma unroll
                for (int r = 0; r < 4; r++) ar[r] = __shfl(alpha, quad * 4 + r, 16);
                #pragma unroll
                for (int nt = 0; nt < 4; nt++)
                    #pragma unroll
                    for (int r = 0; r < 4; r++) oacc[nt][r] *= ar[r];
            }

            __threadfence_block();

            __builtin_amdgcn_s_setprio(1);
            #pragma unroll
            for (int ks2 = 0; ks2 < 2; ks2++) {
                v8hf ph = ldhf8(&plds[wave][col][((ks2 * 8 + quad * 2) ^ psw) * 4]);
                #pragma unroll
                for (int nt = 0; nt < 4; nt++) {
                    const int row = nt * 16 + col;
                    const int g = (ks2 * 4 + quad) ^ (row & 7);
                    v8hf vh = ldhf8(&vd[(row * 8 + g) * 8]);
                    oacc[nt] = MFMA16(ph, vh, oacc[nt]);
                }
            }
            __builtin_amdgcn_s_setprio(0);
        }

        if (!has_nxt) break;
        n_cur = n_nxt; c_cur = c_nxt;
        for (int i = 0; i < stride; i++) if (has_nxt) advance1();
        t++;
    }

    if (stride == 2) {             // split: emit unnormalized partials
        if (quad == 0) {
            const size_t r = srow0 + wave * 16 + col;
            ml[(r * 2 + split) * 2 + 0] = m_i;
            ml[(r * 2 + split) * 2 + 1] = l_i;
        }
        #pragma unroll
        for (int nt = 0; nt < 4; nt++)
            #pragma unroll
            for (int r = 0; r < 4; r++) {
                const size_t rq = srow0 + wave * 16 + quad * 4 + r;
                po[(rq * 2 + split) * 64 + nt * 16 + col] = oacc[nt][r];
            }
        return;
    }

    const int b = bh / NH, h = bh % NH;
    const float invl = 1.f / l_i;
    float ir[4];
    #pragma unroll
    for (int r = 0; r < 4; r++) ir[r] = __shfl(invl, quad * 4 + r, 16);
    #pragma unroll
    for (int nt = 0; nt < 4; nt++)
        #pragma unroll
        for (int r = 0; r < 4; r++) {
            const int qi = qw0 + quad * 4 + r;
            const size_t idx = ((size_t)b * SEQN + qi) * HID + h * DH + nt * 16 + col;
            aoh[idx] = f2h(oacc[nt][r] * ir[r]);
        }
}

// ---------------------------------------------------------------------------
// Merge the two KV-split partials for q-rows 1024..2047 of each bh.
// grid = 24576*16/256 = 1536, float4-vectorized (4 d-elems per thread).
__global__ __launch_bounds__(256)
void attn_combine_k(const float* __restrict__ po, const float* __restrict__ ml,
                    u16* __restrict__ aoh)
{
    const int g = blockIdx.x * 256 + threadIdx.x;   // 0..393215
    const int d4 = (g & 15) * 4;
    const size_t row = (size_t)(g >> 4);            // 0..24575
    const int bh = (int)(row >> 10);
    const int qlocal = (int)(row & 1023);
    const float m0 = ml[(row * 2 + 0) * 2 + 0], l0 = ml[(row * 2 + 0) * 2 + 1];
    const float m1 = ml[(row * 2 + 1) * 2 + 0], l1 = ml[(row * 2 + 1) * 2 + 1];
    const float m  = fmaxf(m0, m1);
    const float a0 = (m0 == NEG_INF) ? 0.f : exp2f((m0 - m) * EXP2C);
    const float a1 = (m1 == NEG_INF) ? 0.f : exp2f((m1 - m) * EXP2C);
    const float inv = 1.f / (l0 * a0 + l1 * a1);
    const float4 p0 = *(const float4*)&po[(row * 2 + 0) * 64 + d4];
    const float4 p1 = *(const float4*)&po[(row * 2 + 1) * 64 + d4];
    ushort4 ov;
    ov.x = f2h((p0.x * a0 + p1.x * a1) * inv);
    ov.y = f2h((p0.y * a0 + p1.y * a1) * inv);
    ov.z = f2h((p0.z * a0 + p1.z * a1) * inv);
    ov.w = f2h((p0.w * a0 + p1.w * a1) * inv);
    const int b = bh / NH, h = bh % NH;
    const int q = SPLIT_ROWS + qlocal;
    *(ushort4*)&aoh[((size_t)b * SEQN + q) * HID + h * DH + d4] = ov;
}

// ---------------------------------------------------------------------------
extern "C" void kernel_launch(void* const* d_in, const int* in_sizes, int n_in,
                              void* d_out, int out_size, void* d_ws, size_t ws_size,
                              hipStream_t stream)
{
    const float* X  = (const float*)d_in[0];
    const float* Wq = (const float*)d_in[1];
    const float* Wk = (const float*)d_in[2];
    const float* Wv = (const float*)d_in[3];
    const float* Wo = (const float*)d_in[4];
    float* out = (float*)d_out;

    char* p = (char*)d_ws;
    float* q32 = (float*)p;                p += (size_t)NTOK*HID*4;
    u16* kh16 = (u16*)p;                   p += (size_t)NTOK*HID*2;
    u16* vth  = (u16*)p;                   p += (size_t)NTOK*HID*2;
    u16* Xh   = (u16*)p;                   p += (size_t)NTOK*HID*2;   // aoh alias
    u16* Xl   = (u16*)p;                   p += (size_t)NTOK*HID*2;
    u16* Wq2  = (u16*)p;                   p += (size_t)HID*HID*2*2;
    u16* Wk2  = (u16*)p;                   p += (size_t)HID*HID*2*2;
    u16* Wv2  = (u16*)p;                   p += (size_t)HID*HID*2*2;
    u16* Wo2  = (u16*)p;                   p += (size_t)HID*HID*2*2;
    float* partial = (float*)p;            p += (size_t)BATCH*NH*NB*2*64*4;
    float* reps    = (float*)p;            p += (size_t)BATCH*NH*NB*DH*4;   // unused (layout keep)
    unsigned* selm = (unsigned*)p;         p += (size_t)BATCH*NH*SEQN*4;    // unused (layout keep)
    float2* tab    = (float2*)p;           p += (size_t)SEQN*32*8;
    u16* aoh = Xh;   // X splits dead after projections
    (void)reps; (void)selm;

    // KV-split partials alias Xl+Wq2+Wk2+Wv2 (dead after qkv gemm):
    // po = 24*1024*2*64*4 = 12,582,912 B; ml = 24*1024*2*2*4 = 786,432 B;
    // sum = 13,369,344 B == sizeof(Xl)+3*sizeof(Wsplit). Ends exactly at Wo2.
    float* po = (float*)Xl;
    float* ml = po + (size_t)NBH * SPLIT_ROWS * 2 * 64;

    preproc_k<<<dim3(5632), 256, 0, stream>>>(X, Wq, Wk, Wv, Wo, tab,
                                              Xh, Xl, Wq2, Wk2, Wv2, Wo2);

    qkv_fused_gemm_k<<<dim3(1152), 256, 0, stream>>>(
        Xh, Xl, Wq2, Wk2, Wv2, tab, q32, kh16, vth, partial);

    moba_attn_k<<<dim3(1152), 256, 0, stream>>>(
        q32, kh16, vth, partial, aoh, po, ml);

    attn_combine_k<<<dim3(1536), 256, 0, stream>>>(po, ml, aoh);

    out_gemm_mfma_k<<<dim3(768), 256, 0, stream>>>(aoh, Wo2, out);
}

// Round 12
// 196.974 us; speedup vs baseline: 1.0706x; 1.0706x over previous
//
#include <hip/hip_runtime.h>
#include <math.h>

// MoBA attention, round 21: register-resident top-k argmax (rule #20 fix).
// r17-r20's argmax used `double sc[NB]` with RUNTIME-indexed writes
// (sc[cur]=..., loop from cur+1) -> compiler allocates sc in SCRATCH; r20
// ran it on all 256 threads -> 4x scratch traffic -> attn 64->73us. Fix:
// branchless fully-unrolled selects (constant indices only) -> registers.
// Identical fp64 values + ascending-n strict-greater argmax -> bit-identical
// masks. Everything else r20 verbatim (wave-causal skip, stride-9 dsc,
// vectorized combine, defer-max, heavy-first order, dual-split gemms).

#define HID   768
#define NH    12
#define DH    64
#define SEQN  2048
#define BATCH 2
#define NTOK  (BATCH*SEQN)   // 4096
#define NB    8
#define BLKSZ 256
#define NEG_INF (-__builtin_huge_valf())
#define POS_INF (__builtin_huge_valf())
#define LO_SCALE 2048.0f
#define LO_INV   (1.0f/2048.0f)
#define EXP2C    0.18033688f   // 0.125 * log2(e)

// split geometry: per bh, q-rows 1024..2047 are split 2-way
#define SPLIT_ROWS 1024
#define NBH   (BATCH*NH)       // 24

typedef unsigned short u16;
typedef _Float16 v8hf __attribute__((ext_vector_type(8)));
typedef float    v4f  __attribute__((ext_vector_type(4)));

__device__ __forceinline__ u16 f2h(float x) {
    _Float16 h = (_Float16)x;
    return __builtin_bit_cast(u16, h);
}
__device__ __forceinline__ float h2f(u16 u) {
    return (float)__builtin_bit_cast(_Float16, u);
}
__device__ __forceinline__ v8hf ldhf8(const u16* p) {
    return *reinterpret_cast<const v8hf*>(p);
}
__device__ __forceinline__ void g2lds16(const u16* g, u16* l) {
    __builtin_amdgcn_global_load_lds(
        (const __attribute__((address_space(1))) void*)g,
        (__attribute__((address_space(3))) void*)l, 16, 0, 0);
}
#define MFMA16(a, b, c) __builtin_amdgcn_mfma_f32_16x16x32_f16(a, b, c, 0, 0, 0)

// heavy-first permutation: slot -> round-10 unit id (u<16: unsplit qb=u;
// u>=16: qb=16+((u-16)>>1), split=(u-16)&1). Ordered by descending static
// tile upper-bound: ub_unsplit(qb)=qb+1, ub_split(qb)=(qb+2)>>1.
__device__ const int g_uord[48] = {
    46,47,44,45,15,  // ub 16: qb31 s0/s1, qb30 s0/s1, qb15
    42,43,40,41,14,  // ub 15
    38,39,36,37,13,  // ub 14
    34,35,32,33,12,  // ub 13
    30,31,28,29,11,  // ub 12
    26,27,24,25,10,  // ub 11
    22,23,20,21, 9,  // ub 10
    18,19,16,17, 8,  // ub  9
     7, 6, 5, 4, 3, 2, 1, 0
};

// ---------------------------------------------------------------------------
// Fused preprocessing, x4-vectorized: X split (blocks 0-3071), W splits
// (3072-5375), RoPE table (5376-5631).
__global__ __launch_bounds__(256)
void preproc_k(const float* __restrict__ X,  const float* __restrict__ Wq,
               const float* __restrict__ Wk, const float* __restrict__ Wv,
               const float* __restrict__ Wo, float2* __restrict__ tab,
               u16* __restrict__ Xh, u16* __restrict__ Xl,
               u16* __restrict__ Wq2, u16* __restrict__ Wk2,
               u16* __restrict__ Wv2, u16* __restrict__ Wo2)
{
    const int NW = HID * HID;
    const int id = blockIdx.x;
    const int tid = threadIdx.x;
    if (id < 3072) {                        // X -> f16 hi/lo(x2048), 4 elems
        const int i = (id * 256 + tid) * 4;
        const float4 x4 = *(const float4*)&X[i];
        const float xf[4] = {x4.x, x4.y, x4.z, x4.w};
        ushort4 h4, l4;
        u16* hp = (u16*)&h4; u16* lp = (u16*)&l4;
        #pragma unroll
        for (int j = 0; j < 4; j++) {
            const u16 h = f2h(xf[j]);
            hp[j] = h;
            lp[j] = f2h((xf[j] - h2f(h)) * LO_SCALE);
        }
        *(ushort4*)&Xh[i] = h4;
        *(ushort4*)&Xl[i] = l4;
    } else if (id < 5376) {                 // 4 weight splits, 4 elems
        const int j4 = ((id - 3072) * 256 + tid) * 4;
        const int z = j4 / NW, i = j4 - z * NW;
        const float* src = (z == 0) ? Wq : (z == 1) ? Wk : (z == 2) ? Wv : Wo;
        u16* dst = (z == 0) ? Wq2 : (z == 1) ? Wk2 : (z == 2) ? Wv2 : Wo2;
        const float4 x4 = *(const float4*)&src[i];
        const float xf[4] = {x4.x, x4.y, x4.z, x4.w};
        ushort4 h4, l4;
        u16* hp = (u16*)&h4; u16* lp = (u16*)&l4;
        #pragma unroll
        for (int j = 0; j < 4; j++) {
            const u16 h = f2h(xf[j]);
            hp[j] = h;
            lp[j] = f2h((xf[j] - h2f(h)) * LO_SCALE);
        }
        *(ushort4*)&dst[i] = h4;
        *(ushort4*)&dst[i + NW] = l4;
    } else {                                // RoPE table (numpy fp32 op order)
        const int i = (id - 5376) * 256 + tid;
        const int s = i >> 5, f = i & 31;
        const double y  = exp((double)f * (log(10000.0) / 32.0));
        const float yf = (float)y;
        const float invf = 1.0f / yf;
        const float ang  = (float)s * invf;
        tab[i] = make_float2((float)sin((double)ang), (float)cos((double)ang));
    }
}

// ---------------------------------------------------------------------------
// Single-pass 128x64 dual-split mainloop. Per K-chunk both A splits (hi,lo)
// and both B splits are staged; products accumulate into acc01 (lo-pair) and
// acc2 (hi*hi). hasC0=false (V) skips the Al*Bh product and Al staging.
__device__ __forceinline__
void qkv_mainloop(const u16* __restrict__ Ah, const u16* __restrict__ Al,
                  const u16* __restrict__ Bh, const u16* __restrict__ Bl,
                  int m0, int nb0, bool hasC0,
                  u16* As, u16* Bs, v4f acc01[2][4], v4f acc2[2][4])
{
    const int tid = threadIdx.x;
    const int w = tid >> 6, lane = tid & 63;
    const int col = lane & 15, quad = lane >> 4;
    const int AOFF = 128 * 64, BOFF = 64 * 64;

    int a_row[4], a_gl[4];
    #pragma unroll
    for (int r = 0; r < 4; r++) {
        const int g = r * 256 + tid;
        a_row[r] = g >> 3;
        a_gl[r]  = (g & 7) ^ (a_row[r] & 7);
    }
    int b_row[2], b_gl[2];
    #pragma unroll
    for (int r = 0; r < 2; r++) {
        const int g = r * 256 + tid;
        b_row[r] = g >> 3;
        b_gl[r]  = (g & 7) ^ (b_row[r] & 7);
    }

    for (int itc = 0; itc < HID / 64; itc++) {
        const int k0 = itc * 64;
        __syncthreads();
        #pragma unroll
        for (int r = 0; r < 4; r++)
            g2lds16(Ah + (size_t)(m0 + a_row[r]) * HID + k0 + a_gl[r] * 8,
                    &As[(r * 256 + w * 64) * 8]);
        if (hasC0) {
            #pragma unroll
            for (int r = 0; r < 4; r++)
                g2lds16(Al + (size_t)(m0 + a_row[r]) * HID + k0 + a_gl[r] * 8,
                        &As[AOFF + (r * 256 + w * 64) * 8]);
        }
        #pragma unroll
        for (int r = 0; r < 2; r++) {
            g2lds16(Bh + (size_t)(nb0 + b_row[r]) * HID + k0 + b_gl[r] * 8,
                    &Bs[(r * 256 + w * 64) * 8]);
            g2lds16(Bl + (size_t)(nb0 + b_row[r]) * HID + k0 + b_gl[r] * 8,
                    &Bs[BOFF + (r * 256 + w * 64) * 8]);
        }
        __syncthreads();
        #pragma unroll
        for (int ks = 0; ks < 2; ks++) {
            v8hf afh[2], afl[2], bfh[4], bfl[4];
            #pragma unroll
            for (int mt = 0; mt < 2; mt++) {
                const int row = w * 32 + mt * 16 + col;
                const int gph = (ks * 4 + quad) ^ (row & 7);
                afh[mt] = ldhf8(&As[row * 64 + gph * 8]);
                if (hasC0) afl[mt] = ldhf8(&As[AOFF + row * 64 + gph * 8]);
            }
            #pragma unroll
            for (int nt = 0; nt < 4; nt++) {
                const int row = nt * 16 + col;
                const int gph = (ks * 4 + quad) ^ (row & 7);
                bfh[nt] = ldhf8(&Bs[row * 64 + gph * 8]);
                bfl[nt] = ldhf8(&Bs[BOFF + row * 64 + gph * 8]);
            }
            #pragma unroll
            for (int mt = 0; mt < 2; mt++)
                #pragma unroll
                for (int nt = 0; nt < 4; nt++) {
                    if (hasC0)
                        acc01[mt][nt] = MFMA16(afl[mt], bfh[nt], acc01[mt][nt]);
                    acc01[mt][nt] = MFMA16(afh[mt], bfl[nt], acc01[mt][nt]);
                    acc2[mt][nt]  = MFMA16(afh[mt], bfh[nt], acc2[mt][nt]);
                }
        }
    }
    __syncthreads();
}

// ---------------------------------------------------------------------------
// Fused QKV. grid = 1152: 36 n-tiles (Q 0-11, K 12-23, V 24-35) x 32 m-tiles,
// XCD-partitioned by m. Single-pass dual-split staging (48 KB LDS).
__global__ __launch_bounds__(256, 3)
void qkv_fused_gemm_k(const u16* __restrict__ Xh, const u16* __restrict__ Xl,
                      const u16* __restrict__ Wq2, const u16* __restrict__ Wk2,
                      const u16* __restrict__ Wv2, const float2* __restrict__ tab,
                      float* __restrict__ q32, u16* __restrict__ kh16,
                      u16* __restrict__ vth, float* __restrict__ partial)
{
    __shared__ u16 As[2 * 128 * 64];   // 32 KB (hi | lo)
    __shared__ u16 Bs[2 * 64 * 64];    // 16 KB (hi | lo)
    float (*psum)[64] = (float(*)[64])As;   // overlay: post-loop use only

    const int NW = HID * HID;
    const int id    = blockIdx.x;
    const int xcd   = id & 7, loc = id >> 3;      // 144 per XCD
    const int mtile = xcd * 4 + (loc & 3);
    const int ntile = loc >> 2;                   // 0..35
    const int m0  = mtile * 128;
    const int mat = ntile / 12;
    const int nb0 = (ntile - mat * 12) * 64;
    const u16* Bh = (mat == 0) ? Wq2 : (mat == 1) ? Wk2 : Wv2;

    v4f acc01[2][4] = {}, acc2[2][4] = {};
    qkv_mainloop(Xh, Xl, Bh, Bh + NW, m0, nb0, mat != 2, As, Bs, acc01, acc2);

    v4f acc[2][4];
    #pragma unroll
    for (int mt = 0; mt < 2; mt++)
        #pragma unroll
        for (int nt = 0; nt < 4; nt++)
            #pragma unroll
            for (int r = 0; r < 4; r++)
                acc[mt][nt][r] = acc01[mt][nt][r] * LO_INV + acc2[mt][nt][r];

    const int tid = threadIdx.x;
    const int w = tid >> 6, lane = tid & 63;
    const int col = lane & 15, quad = lane >> 4;
    const int b = m0 >> 11;
    const int h = nb0 >> 6;
    const size_t bh = (size_t)b * NH + h;

    if (mat == 2) {                // V: transposed f16 store
        #pragma unroll
        for (int nt = 0; nt < 4; nt++) {
            const int d = nt * 16 + col;
            #pragma unroll
            for (int mt = 0; mt < 2; mt++) {
                const int m = m0 + w * 32 + mt * 16 + quad * 4;
                const int s = m & (SEQN - 1);
                ushort4 pk = make_ushort4(f2h(acc[mt][nt][0]), f2h(acc[mt][nt][1]),
                                          f2h(acc[mt][nt][2]), f2h(acc[mt][nt][3]));
                *(ushort4*)&vth[(bh * DH + d) * SEQN + s] = pk;
            }
        }
        return;
    }

    // Q/K: RoPE (partner dim d^32 = acc[mt][nt^2], same lane)
    float vsum[4] = {0.f, 0.f, 0.f, 0.f};
    #pragma unroll
    for (int mt = 0; mt < 2; mt++) {
        #pragma unroll
        for (int nt = 0; nt < 4; nt++) {
            const int d = nt * 16 + col;
            #pragma unroll
            for (int r = 0; r < 4; r++) {
                const int m = m0 + w * 32 + mt * 16 + quad * 4 + r;
                const int s = m & (SEQN - 1);
                const float part = acc[mt][nt ^ 2][r];
                const float2 sc = tab[(s << 5) + (d & 31)];
                const float val = (d < 32) ? acc[mt][nt][r] * sc.y - part * sc.x
                                           : acc[mt][nt][r] * sc.y + part * sc.x;
                const size_t idx = (bh * SEQN + s) * DH + d;
                if (mat == 0) {
                    q32[idx] = val;
                } else {
                    kh16[idx] = f2h(val);
                    vsum[nt] += val;
                }
            }
        }
    }
    if (mat == 1) {                // deterministic 128-token block partials
        #pragma unroll
        for (int nt = 0; nt < 4; nt++) {
            float v = vsum[nt];
            v += __shfl_xor(v, 16);
            v += __shfl_xor(v, 32);
            if (quad == 0) psum[w][nt * 16 + col] = v;
        }
        __syncthreads();
        if (tid < 64) {
            const float s4 = (psum[0][tid] + psum[1][tid])
                           + (psum[2][tid] + psum[3][tid]);
            const int nblk = (m0 & (SEQN - 1)) >> 8;
            const int half = (m0 >> 7) & 1;
            partial[((bh * NB + nblk) * 2 + half) * 64 + tid] = s4;
        }
    }
}

// ---------------------------------------------------------------------------
// Output projection: 64x64 tiles, 768 wgs (3/CU), single-pass dual-split.
__global__ __launch_bounds__(256, 3)
void out_gemm_mfma_k(const u16* __restrict__ Ah, const u16* __restrict__ Wo2,
                     float* __restrict__ C)
{
    __shared__ u16 As[64 * 64];        // 8 KB
    __shared__ u16 Bs[2 * 64 * 64];    // 16 KB (hi | lo)
    const int BOFF = 64 * 64;

    const int NW = HID * HID;
    const int id    = blockIdx.x;                 // 768
    const int xcd   = id & 7, loc = id >> 3;      // 96 per XCD
    const int mtile = xcd * 8 + (loc & 7);        // 64 m-tiles
    const int ntile = loc >> 3;                   // 0..11
    const int m0 = mtile * 64, n0 = ntile * 64;
    const int tid = threadIdx.x;
    const int w = tid >> 6, lane = tid & 63;
    const int col = lane & 15, quad = lane >> 4;

    const int r0 = tid >> 3,         gl0 = (tid & 7) ^ (r0 & 7);
    const int r1 = (256 + tid) >> 3, gl1 = ((256 + tid) & 7) ^ (r1 & 7);

    const u16* Bhp = Wo2;            // hi
    const u16* Blp = Wo2 + NW;       // lo

    v4f accL[4] = {}, accH[4] = {};
    for (int itc = 0; itc < HID / 64; itc++) {
        const int k0 = itc * 64;
        __syncthreads();
        g2lds16(Ah  + (size_t)(m0 + r0) * HID + k0 + gl0 * 8, &As[(w * 64) * 8]);
        g2lds16(Ah  + (size_t)(m0 + r1) * HID + k0 + gl1 * 8, &As[(256 + w * 64) * 8]);
        g2lds16(Bhp + (size_t)(n0 + r0) * HID + k0 + gl0 * 8, &Bs[(w * 64) * 8]);
        g2lds16(Bhp + (size_t)(n0 + r1) * HID + k0 + gl1 * 8, &Bs[(256 + w * 64) * 8]);
        g2lds16(Blp + (size_t)(n0 + r0) * HID + k0 + gl0 * 8, &Bs[BOFF + (w * 64) * 8]);
        g2lds16(Blp + (size_t)(n0 + r1) * HID + k0 + gl1 * 8, &Bs[BOFF + (256 + w * 64) * 8]);
        __syncthreads();
        #pragma unroll
        for (int ks = 0; ks < 2; ks++) {
            const int arow = w * 16 + col;
            v8hf a = ldhf8(&As[arow * 64 + (((ks * 4 + quad) ^ (arow & 7))) * 8]);
            #pragma unroll
            for (int nt = 0; nt < 4; nt++) {
                const int row = nt * 16 + col;
                const int g = (ks * 4 + quad) ^ (row & 7);
                accH[nt] = MFMA16(a, ldhf8(&Bs[row * 64 + g * 8]), accH[nt]);
                accL[nt] = MFMA16(a, ldhf8(&Bs[BOFF + row * 64 + g * 8]), accL[nt]);
            }
        }
    }

    #pragma unroll
    for (int nt = 0; nt < 4; nt++)
        #pragma unroll
        for (int r = 0; r < 4; r++) {
            const int m = m0 + w * 16 + quad * 4 + r;
            C[(size_t)m * HID + n0 + nt * 16 + col] =
                accL[nt][r] * LO_INV + accH[nt][r];
        }
}

// ---------------------------------------------------------------------------
// f16 MFMA flash attention (r16 mainloop: double-buffered K+V, one
// __syncthreads per tile, heavy-first order, 40 KB LDS, 4 blocks/CU) with
// parallel inline reps+top-k prologue (REGISTER-resident branchless argmax),
// defer-max softmax, and wave-causal tile skip. grid = 1152.
__global__ __launch_bounds__(256, 4)
void moba_attn_k(const float* __restrict__ q32, const u16* __restrict__ kh16,
                 const u16* __restrict__ vth, const float* __restrict__ partial,
                 u16* __restrict__ aoh, float* __restrict__ po,
                 float* __restrict__ ml)
{
    __shared__ u16 kbuf[2][64 * 64];
    __shared__ u16 vbuf[2][64 * 64];
    __shared__ u16 plds[4][16][64];
    // prologue overlays (all dead before first stage(); fenced by barriers):
    unsigned* s_uni = (unsigned*)&plds[0][0][0];
    float (*rs)[DH + 4] = (float(*)[DH + 4])&kbuf[0][0];  // 8x68 fl = 2176 B
    double* dsc     = (double*)&kbuf[1][0];               // [qi*9+n], 4608 B
    float4* qv4     = (float4*)&vbuf[0][0];               // 64 rows x 16 f4,
                                                          // XOR-swizzled

    const int id  = blockIdx.x;                 // 0..1151
    const int xcd = id & 7, loc = id >> 3;      // 0..143
    const int bh  = xcd * 3 + loc / 48;
    const int u   = g_uord[loc % 48];           // heavy-first permutation
    int qb, split, stride;
    if (u < 16) { qb = u;                 split = 0;          stride = 1; }
    else        { qb = 16 + ((u - 16) >> 1); split = (u - 16) & 1; stride = 2; }
    const int q0  = qb * 64;
    const int cur = q0 >> 8;
    const int tid = threadIdx.x;
    const int wave = tid >> 6, lane = tid & 63;
    const int col = lane & 15, quad = lane >> 4;
    const int qw0 = q0 + wave * 16;
    const int qpos = qw0 + col;
    const size_t bhS = (size_t)bh * SEQN;
    const size_t bhV = (size_t)bh * DH;

    // --- prologue: stage Q (swizzled) + reps (padded rows) ---
    if (tid == 0) *s_uni = 0;
    {
        const float4* src = (const float4*)&q32[(bhS + q0) * DH];
        #pragma unroll
        for (int i = 0; i < 4; i++) {
            const int L = tid + i * 256;            // 0..1023
            const int r = L >> 4, j = L & 15;
            qv4[r * 16 + (j ^ (r & 7))] = src[L];
        }
    }
    for (int idx = tid; idx < NB * DH; idx += 256) {
        const int n = idx >> 6, d = idx & 63;
        const float* pp = &partial[(size_t)((bh * NB + n) * 2) * 64 + d];
        const double s = (double)pp[0] + (double)pp[64];
        rs[n][d] = (float)(s * (1.0 / 256.0));
    }
    __syncthreads();

    // 512 dots (q-row qi, block n), 2/thread; per-dot d-ascending fp64 order
    // identical to the standalone select_topk_k -> bit-identical masks.
    #pragma unroll
    for (int hh = 0; hh < 2; hh++) {
        const int e = tid + hh * 256;               // 0..511
        const int qi = e >> 3, n = e & 7;
        double s = 0.0;
        for (int c = 0; c < 16; c++) {
            const float4 a = qv4[qi * 16 + (c ^ (qi & 7))];
            const float4 b = *(const float4*)&rs[n][c * 4];
            s += (double)a.x * (double)b.x;
            s += (double)a.y * (double)b.y;
            s += (double)a.z * (double)b.z;
            s += (double)a.w * (double)b.w;
        }
        dsc[qi * 9 + n] = s;
    }
    __syncthreads();

    // per-thread argmax for this thread's own q-row; branchless, constant
    // indices only -> stays in registers (no scratch). Same fp64 values and
    // ascending-n strict-greater selection as the standalone kernel.
    unsigned mymask;
    {
        const int qrow = wave * 16 + col;
        double sc[NB];
        #pragma unroll
        for (int n = 0; n < NB; n++) {
            double v = dsc[qrow * 9 + n] * 0.125;
            v = (n > cur) ? -1e300 : v;
            sc[n] = (n == cur) ? 1e300 : v;
        }
        unsigned m = 0;
        #pragma unroll
        for (int p = 0; p < 3; p++) {
            int bi = -1; double bv = 0.0;
            #pragma unroll
            for (int n = 0; n < NB; n++) {
                const bool take = !((m >> n) & 1) && (bi < 0 || sc[n] > bv);
                bi = take ? n : bi;
                bv = take ? sc[n] : bv;
            }
            m |= 1u << bi;
        }
        mymask = m;
    }

    unsigned uw = mymask;
    #pragma unroll
    for (int off = 1; off < 16; off <<= 1) uw |= __shfl_xor(uw, off);
    if (lane == 0) atomicOr(s_uni, uw);
    const unsigned wmask = __builtin_amdgcn_readfirstlane(uw);  // wave's 16-q union

    v8hf qh[2], ql[2];
    {
        const int qrow = wave * 16 + col;
        #pragma unroll
        for (int ks = 0; ks < 2; ks++) {
            const int j0 = ks * 8 + quad * 2;
            const float4 f0 = qv4[qrow * 16 + (j0 ^ (qrow & 7))];
            const float4 f1 = qv4[qrow * 16 + ((j0 + 1) ^ (qrow & 7))];
            float qf[8] = {f0.x, f0.y, f0.z, f0.w, f1.x, f1.y, f1.z, f1.w};
            union { u16 u[8]; v8hf h; } uh, ul;
            #pragma unroll
            for (int j = 0; j < 8; j++) {
                u16 hb = f2h(qf[j]);
                uh.u[j] = hb;
                ul.u[j] = f2h((qf[j] - h2f(hb)) * LO_SCALE);
            }
            qh[ks] = uh.h; ql[ks] = ul.h;
        }
    }
    __syncthreads();   // s_uni final; qv4/dsc reads done (bufs reusable)
    const unsigned uni = __builtin_amdgcn_readfirstlane(*s_uni);

    // tile enumerator: split s starts at tile index s, advances by `stride`
    int n_nxt = __builtin_ctz(uni), c_nxt = 0;
    bool has_nxt = true;
    auto c2max = [&](int n) { return (n == cur) ? ((q0 + 63 - n * BLKSZ) >> 6) : 3; };
    auto advance1 = [&]() {
        if (c_nxt < c2max(n_nxt)) { c_nxt++; return; }
        for (int nn = n_nxt + 1; nn < NB; nn++)
            if ((uni >> nn) & 1) { n_nxt = nn; c_nxt = 0; return; }
        has_nxt = false;
    };
    for (int i = 0; i < split; i++) if (has_nxt) advance1();
    int n_cur = n_nxt, c_cur = c_nxt;
    const bool cur_valid = has_nxt;

    const size_t srow0 = (size_t)bh * SPLIT_ROWS + (q0 - SPLIT_ROWS);  // split rows only

    if (!cur_valid) {   // empty split (defensive; cur block always has >=1 tile)
        if (stride == 2) {
            if (quad == 0) {
                const size_t r = srow0 + wave * 16 + col;
                ml[(r * 2 + split) * 2 + 0] = NEG_INF;
                ml[(r * 2 + split) * 2 + 1] = 0.f;
            }
            #pragma unroll
            for (int nt = 0; nt < 4; nt++)
                #pragma unroll
                for (int r = 0; r < 4; r++) {
                    const size_t rq = srow0 + wave * 16 + quad * 4 + r;
                    po[(rq * 2 + split) * 64 + nt * 16 + col] = 0.f;
                }
        }
        return;
    }
    for (int i = 0; i < stride; i++) if (has_nxt) advance1();

    const int sg_row0 = tid >> 3;
    const int sg_gl0  = (tid & 7) ^ (sg_row0 & 7);
    const int sg_row1 = (256 + tid) >> 3;
    const int sg_gl1  = ((256 + tid) & 7) ^ (sg_row1 & 7);
    auto stage = [&](int n, int c2, int buf) {
        const int kb = n * BLKSZ + c2 * 64;
        u16* kd = (u16*)kbuf[buf];
        u16* vd = (u16*)vbuf[buf];
        const size_t ks0 = (bhS + kb + sg_row0) * DH + sg_gl0 * 8;
        const size_t ks1 = (bhS + kb + sg_row1) * DH + sg_gl1 * 8;
        const size_t vs0 = (bhV + sg_row0) * SEQN + kb + sg_gl0 * 8;
        const size_t vs1 = (bhV + sg_row1) * SEQN + kb + sg_gl1 * 8;
        g2lds16(kh16 + ks0, kd + (wave * 64) * 8);
        g2lds16(kh16 + ks1, kd + (256 + wave * 64) * 8);
        g2lds16(vth + vs0, vd + (wave * 64) * 8);
        g2lds16(vth + vs1, vd + (256 + wave * 64) * 8);
    };

    const v4f zero4 = {0.f, 0.f, 0.f, 0.f};
    v4f oacc[4] = {zero4, zero4, zero4, zero4};
    float m_i = NEG_INF, l_i = 0.f;
    const int psw = (col & 7) << 1;

    stage(n_cur, c_cur, 0);
    int t = 0;
    while (true) {
        __syncthreads();
        if (has_nxt) stage(n_nxt, c_nxt, (t + 1) & 1);

        const int n  = n_cur;
        const int kb = n * BLKSZ + c_cur * 64;
        const bool iscur = (n == cur);
        const float selinf = ((mymask >> n) & 1) ? 0.f : POS_INF;
        const bool need_mask = iscur && (kb + 63 > qw0);
        const u16* kd = (const u16*)kbuf[t & 1];
        const u16* vd = (const u16*)vbuf[t & 1];

        // skip body if none of this wave's 16 queries select block n, or the
        // chunk is entirely beyond this wave's causal range (kb > qw0+15:
        // all scores masked to -inf => p=0, rm=-inf => m,l,oacc unchanged).
        if (((wmask >> n) & 1) && (!iscur || kb <= qw0 + 15)) {
            v4f sf[4];
            __builtin_amdgcn_s_setprio(1);
            #pragma unroll
            for (int mt = 0; mt < 4; mt++) {
                const int row = mt * 16 + col;
                const int r7 = row & 7;
                v8hf kh0 = ldhf8(&kd[(row * 8 + (quad ^ r7)) * 8]);
                v8hf kh1 = ldhf8(&kd[(row * 8 + ((4 + quad) ^ r7)) * 8]);
                v4f c = zero4;
                c = MFMA16(kh0, ql[0], c);
                c = MFMA16(kh1, ql[1], c);
                #pragma unroll
                for (int r = 0; r < 4; r++) c[r] *= LO_INV;
                c = MFMA16(kh0, qh[0], c);
                c = MFMA16(kh1, qh[1], c);
                sf[mt] = c;
            }
            __builtin_amdgcn_s_setprio(0);

            if (need_mask) {
                #pragma unroll
                for (int mt = 0; mt < 4; mt++)
                    #pragma unroll
                    for (int r = 0; r < 4; r++) {
                        const int kidx = kb + mt * 16 + quad * 4 + r;
                        sf[mt][r] = (kidx <= qpos) ? sf[mt][r] : NEG_INF;
                    }
            }

            // tree max (depth 4 instead of 16)
            const float t0 = fmaxf(fmaxf(sf[0][0], sf[0][1]), fmaxf(sf[0][2], sf[0][3]));
            const float t1 = fmaxf(fmaxf(sf[1][0], sf[1][1]), fmaxf(sf[1][2], sf[1][3]));
            const float t2 = fmaxf(fmaxf(sf[2][0], sf[2][1]), fmaxf(sf[2][2], sf[2][3]));
            const float t3 = fmaxf(fmaxf(sf[3][0], sf[3][1]), fmaxf(sf[3][2], sf[3][3]));
            float rm = fmaxf(fmaxf(t0, t1), fmaxf(t2, t3));
            rm = fmaxf(rm, __shfl_xor(rm, 16));
            rm = fmaxf(rm, __shfl_xor(rm, 32));
            rm = rm - selinf;

            // defer-max: skip rescale when no lane's max grew by > 8
            // (p then bounded by e^1; m/l/oacc bias consistency kept)
            const bool fast = __all(rm <= m_i + 8.0f) != 0;
            float mnew = m_i, alpha = 1.f;
            if (!fast) {
                mnew  = fmaxf(m_i, rm);
                alpha = (m_i == NEG_INF) ? 0.f : exp2f((m_i - mnew) * EXP2C);
            }
            const float biasC = ((mnew == NEG_INF) ? 0.f : mnew * EXP2C) + selinf;

            float lmt[4];
            #pragma unroll
            for (int mt = 0; mt < 4; mt++) {
                ushort4 hv;
                float p0 = exp2f(fmaf(sf[mt][0], EXP2C, -biasC));
                float p1 = exp2f(fmaf(sf[mt][1], EXP2C, -biasC));
                float p2 = exp2f(fmaf(sf[mt][2], EXP2C, -biasC));
                float p3 = exp2f(fmaf(sf[mt][3], EXP2C, -biasC));
                hv.x = f2h(p0); hv.y = f2h(p1); hv.z = f2h(p2); hv.w = f2h(p3);
                lmt[mt] = (p0 + p1) + (p2 + p3);
                *(ushort4*)&plds[wave][col][((mt * 4 + quad) ^ psw) * 4] = hv;
            }
            float lsum = (lmt[0] + lmt[1]) + (lmt[2] + lmt[3]);
            lsum += __shfl_xor(lsum, 16);
            lsum += __shfl_xor(lsum, 32);

            if (fast) {
                l_i = l_i + lsum;
            } else {
                l_i = l_i * alpha + lsum;
                m_i = mnew;
                float ar[4];
                #pragma unroll
                for (int r = 0; r < 4; r++) ar[r] = __shfl(alpha, quad * 4 + r, 16);
                #pragma unroll
                for (int nt = 0; nt < 4; nt++)
                    #pragma unroll
                    for (int r = 0; r < 4; r++) oacc[nt][r] *= ar[r];
            }

            __threadfence_block();

            __builtin_amdgcn_s_setprio(1);
            #pragma unroll
            for (int ks2 = 0; ks2 < 2; ks2++) {
                v8hf ph = ldhf8(&plds[wave][col][((ks2 * 8 + quad * 2) ^ psw) * 4]);
                #pragma unroll
                for (int nt = 0; nt < 4; nt++) {
                    const int row = nt * 16 + col;
                    const int g = (ks2 * 4 + quad) ^ (row & 7);
                    v8hf vh = ldhf8(&vd[(row * 8 + g) * 8]);
                    oacc[nt] = MFMA16(ph, vh, oacc[nt]);
                }
            }
            __builtin_amdgcn_s_setprio(0);
        }

        if (!has_nxt) break;
        n_cur = n_nxt; c_cur = c_nxt;
        for (int i = 0; i < stride; i++) if (has_nxt) advance1();
        t++;
    }

    if (stride == 2) {             // split: emit unnormalized partials
        if (quad == 0) {
            const size_t r = srow0 + wave * 16 + col;
            ml[(r * 2 + split) * 2 + 0] = m_i;
            ml[(r * 2 + split) * 2 + 1] = l_i;
        }
        #pragma unroll
        for (int nt = 0; nt < 4; nt++)
            #pragma unroll
            for (int r = 0; r < 4; r++) {
                const size_t rq = srow0 + wave * 16 + quad * 4 + r;
                po[(rq * 2 + split) * 64 + nt * 16 + col] = oacc[nt][r];
            }
        return;
    }

    const int b = bh / NH, h = bh % NH;
    const float invl = 1.f / l_i;
    float ir[4];
    #pragma unroll
    for (int r = 0; r < 4; r++) ir[r] = __shfl(invl, quad * 4 + r, 16);
    #pragma unroll
    for (int nt = 0; nt < 4; nt++)
        #pragma unroll
        for (int r = 0; r < 4; r++) {
            const int qi = qw0 + quad * 4 + r;
            const size_t idx = ((size_t)b * SEQN + qi) * HID + h * DH + nt * 16 + col;
            aoh[idx] = f2h(oacc[nt][r] * ir[r]);
        }
}

// ---------------------------------------------------------------------------
// Merge the two KV-split partials for q-rows 1024..2047 of each bh.
// grid = 24576*16/256 = 1536, float4-vectorized (4 d-elems per thread).
__global__ __launch_bounds__(256)
void attn_combine_k(const float* __restrict__ po, const float* __restrict__ ml,
                    u16* __restrict__ aoh)
{
    const int g = blockIdx.x * 256 + threadIdx.x;   // 0..393215
    const int d4 = (g & 15) * 4;
    const size_t row = (size_t)(g >> 4);            // 0..24575
    const int bh = (int)(row >> 10);
    const int qlocal = (int)(row & 1023);
    const float m0 = ml[(row * 2 + 0) * 2 + 0], l0 = ml[(row * 2 + 0) * 2 + 1];
    const float m1 = ml[(row * 2 + 1) * 2 + 0], l1 = ml[(row * 2 + 1) * 2 + 1];
    const float m  = fmaxf(m0, m1);
    const float a0 = (m0 == NEG_INF) ? 0.f : exp2f((m0 - m) * EXP2C);
    const float a1 = (m1 == NEG_INF) ? 0.f : exp2f((m1 - m) * EXP2C);
    const float inv = 1.f / (l0 * a0 + l1 * a1);
    const float4 p0 = *(const float4*)&po[(row * 2 + 0) * 64 + d4];
    const float4 p1 = *(const float4*)&po[(row * 2 + 1) * 64 + d4];
    ushort4 ov;
    ov.x = f2h((p0.x * a0 + p1.x * a1) * inv);
    ov.y = f2h((p0.y * a0 + p1.y * a1) * inv);
    ov.z = f2h((p0.z * a0 + p1.z * a1) * inv);
    ov.w = f2h((p0.w * a0 + p1.w * a1) * inv);
    const int b = bh / NH, h = bh % NH;
    const int q = SPLIT_ROWS + qlocal;
    *(ushort4*)&aoh[((size_t)b * SEQN + q) * HID + h * DH + d4] = ov;
}

// ---------------------------------------------------------------------------
extern "C" void kernel_launch(void* const* d_in, const int* in_sizes, int n_in,
                              void* d_out, int out_size, void* d_ws, size_t ws_size,
                              hipStream_t stream)
{
    const float* X  = (const float*)d_in[0];
    const float* Wq = (const float*)d_in[1];
    const float* Wk = (const float*)d_in[2];
    const float* Wv = (const float*)d_in[3];
    const float* Wo = (const float*)d_in[4];
    float* out = (float*)d_out;

    char* p = (char*)d_ws;
    float* q32 = (float*)p;                p += (size_t)NTOK*HID*4;
    u16* kh16 = (u16*)p;                   p += (size_t)NTOK*HID*2;
    u16* vth  = (u16*)p;                   p += (size_t)NTOK*HID*2;
    u16* Xh   = (u16*)p;                   p += (size_t)NTOK*HID*2;   // aoh alias
    u16* Xl   = (u16*)p;                   p += (size_t)NTOK*HID*2;
    u16* Wq2  = (u16*)p;                   p += (size_t)HID*HID*2*2;
    u16* Wk2  = (u16*)p;                   p += (size_t)HID*HID*2*2;
    u16* Wv2  = (u16*)p;                   p += (size_t)HID*HID*2*2;
    u16* Wo2  = (u16*)p;                   p += (size_t)HID*HID*2*2;
    float* partial = (float*)p;            p += (size_t)BATCH*NH*NB*2*64*4;
    float* reps    = (float*)p;            p += (size_t)BATCH*NH*NB*DH*4;   // unused (layout keep)
    unsigned* selm = (unsigned*)p;         p += (size_t)BATCH*NH*SEQN*4;    // unused (layout keep)
    float2* tab    = (float2*)p;           p += (size_t)SEQN*32*8;
    u16* aoh = Xh;   // X splits dead after projections
    (void)reps; (void)selm;

    // KV-split partials alias Xl+Wq2+Wk2+Wv2 (dead after qkv gemm):
    // po = 24*1024*2*64*4 = 12,582,912 B; ml = 24*1024*2*2*4 = 786,432 B;
    // sum = 13,369,344 B == sizeof(Xl)+3*sizeof(Wsplit). Ends exactly at Wo2.
    float* po = (float*)Xl;
    float* ml = po + (size_t)NBH * SPLIT_ROWS * 2 * 64;

    preproc_k<<<dim3(5632), 256, 0, stream>>>(X, Wq, Wk, Wv, Wo, tab,
                                              Xh, Xl, Wq2, Wk2, Wv2, Wo2);

    qkv_fused_gemm_k<<<dim3(1152), 256, 0, stream>>>(
        Xh, Xl, Wq2, Wk2, Wv2, tab, q32, kh16, vth, partial);

    moba_attn_k<<<dim3(1152), 256, 0, stream>>>(
        q32, kh16, vth, partial, aoh, po, ml);

    attn_combine_k<<<dim3(1536), 256, 0, stream>>>(po, ml, aoh);

    out_gemm_mfma_k<<<dim3(768), 256, 0, stream>>>(aoh, Wo2, out);
}